// Round 12
// baseline (1875.993 us; speedup 1.0000x reference)
//
#include <hip/hip_runtime.h>

// Decoder step — ROUND 12 DIAGNOSTIC: same 218us kernel set as round 9, but
// prep/energy/gates0/fc loop their bodies in-kernel (reps arg, laundered
// pointers) so each becomes a >200us dispatch visible in rocprof top-5 with
// full counters. Outputs identical (idempotent reps; energy adds last rep).

typedef __attribute__((ext_vector_type(8))) short bf16x8;
typedef __attribute__((ext_vector_type(4))) float f32x4;

__device__ __forceinline__ unsigned long launder_u64(unsigned long p){
  asm volatile("" : "+v"(p));
  return p;
}

__device__ __forceinline__ short f2bf(float f){
  __bf16 h = (__bf16)f;
  return __builtin_bit_cast(short, h);
}

__device__ __forceinline__ bf16x8 cvt8(float4 a, float4 b){
  bf16x8 r;
  r[0]=f2bf(a.x); r[1]=f2bf(a.y); r[2]=f2bf(a.z); r[3]=f2bf(a.w);
  r[4]=f2bf(b.x); r[5]=f2bf(b.y); r[6]=f2bf(b.z); r[7]=f2bf(b.w);
  return r;
}

__device__ __forceinline__ bf16x8 ld8_bf(const float* __restrict__ p){
  return cvt8(*(const float4*)p, *(const float4*)(p + 4));
}

__device__ __forceinline__ float fast_tanh(float x){
  x = fminf(fmaxf(x, -15.f), 15.f);
  float t = __expf(2.f * x);
  return (t - 1.f) / (t + 1.f);
}
__device__ __forceinline__ float fast_sig(float x){
  return 1.f / (1.f + __expf(-x));
}

__device__ __forceinline__ void stage16(const void* src, void* dst_lds){
  __builtin_amdgcn_global_load_lds(
      (const __attribute__((address_space(1))) void*)src,
      (__attribute__((address_space(3))) void*)dst_lds, 16, 0, 0);
}

// ---------------------------------------------------------------------------
__global__ __launch_bounds__(256) void prep_all(
    const int* __restrict__ tok, const float* __restrict__ emb,
    const float* __restrict__ hidden, const float* __restrict__ enc,
    const float* __restrict__ attn_w,
    short* __restrict__ encbf, short* __restrict__ Wbf,
    short* __restrict__ A0, short* __restrict__ A1, short* __restrict__ Zb,
    float* __restrict__ sco, int reps)
{
  const int bid = blockIdx.x, t = threadIdx.x;
  for (int r0 = 0; r0 < reps; ++r0){
    const float* encp = (const float*)launder_u64((unsigned long)enc);
    const float* awp  = (const float*)launder_u64((unsigned long)attn_w);
    const float* embp = (const float*)launder_u64((unsigned long)emb);
    const float* hidp = (const float*)launder_u64((unsigned long)hidden);
    if (bid < 4096){
      long i = ((long)bid*256 + t)*8;
      *(bf16x8*)(encbf + i) = ld8_bf(encp + i);
    } else if (bid < 4352){
      int j = (bid-4096)*256 + t;
      int r = j >> 7, c = (j & 127)*8;
      *(bf16x8*)(Wbf + r*1024 + c) = ld8_bf(awp + (long)r*2048 + 1024 + c);
    } else if (bid < 4368){
      int j = (bid-4352)*256 + t;
      int b = j >> 6, e8 = (j & 63)*8;
      bf16x8 v = ld8_bf(embp + (long)tok[b]*512 + e8);
      *(bf16x8*)(A0 + b*2560 + e8) = v;
      *(bf16x8*)(Zb + b*2560 + 2048 + e8) = v;
    } else if (bid < 4400){
      int j = (bid-4368)*256 + t;
      int b = j >> 7, n8 = (j & 127)*8;
      *(bf16x8*)(A0 + b*2560 + 1536 + n8) = ld8_bf(hidp + (long)b*1024 + n8);
      *(bf16x8*)(A1 + b*2048 + 1024 + n8) = ld8_bf(hidp + 65536 + (long)b*1024 + n8);
    } else {
      int j = (bid-4400)*256 + t;
      float4 z = {0.f, 0.f, 0.f, 0.f};
      *(float4*)(sco + j*8) = z;
      *(float4*)(sco + j*8 + 4) = z;
    }
  }
}

// ---------------------------------------------------------------------------
// P[by][64][N] = A_bf16[64,K] @ [W1|W2][N,:]^T on a 256-wide k-slice.
// ---------------------------------------------------------------------------
#define KSL 256
__global__ __launch_bounds__(256) void gemm_lds(
    const short* __restrict__ A, int lda,
    const float* __restrict__ W1, int sW1, int K1,
    const float* __restrict__ W2, int sW2,
    float* __restrict__ P, int N, int reps)
{
  __shared__ short Al[64*256];     // 32 KB
  __shared__ float Wl[3][64*64];   // 48 KB
  const int wv   = threadIdx.x >> 6;
  const int lane = threadIdx.x & 63;
  const int l15  = lane & 15;
  const int lg   = lane >> 4;
  const int nb   = blockIdx.x * 64;
  const int k0   = blockIdx.y * KSL;

  for (int r0 = 0; r0 < reps; ++r0){
    const short* Ap = (const short*)launder_u64((unsigned long)A);
    const float* W; int sW, koff;
    if (k0 < K1){ W = (const float*)launder_u64((unsigned long)W1); sW = sW1; koff = k0; }
    else        { W = (const float*)launder_u64((unsigned long)W2); sW = sW2; koff = k0 - K1; }

    {
      const int r2  = lane >> 5;
      const int c16 = (lane & 31) * 16;
      #pragma unroll
      for (int i = 0; i < 8; ++i){
        int rbase = wv*16 + i*2;
        int row   = rbase + r2;
        const char* src = (const char*)Ap + (long)row*lda*2 + (long)k0*2
                          + (c16 ^ ((row & 7) << 4));
        stage16(src, (void*)(Al + rbase*256));
      }
    }

    auto STAGEW = [&](int bi, int kbase){
      #pragma unroll
      for (int i = 0; i < 4; ++i){
        int row = wv*16 + i*4 + lg;
        const char* src = (const char*)(W + (long)(nb + row)*sW + koff + kbase)
                          + ((l15*16) ^ ((row & 7) << 4));
        stage16(src, (void*)&Wl[bi][(wv*16 + i*4)*64]);
      }
    };

    STAGEW(0, 0);
    STAGEW(1, 64);
    asm volatile("s_waitcnt vmcnt(8)" ::: "memory");
    asm volatile("s_barrier" ::: "memory");

    f32x4 acc[4];
    #pragma unroll
    for (int m = 0; m < 4; ++m) acc[m] = (f32x4){0.f,0.f,0.f,0.f};

    const int  rl = wv*16 + l15;
    const int  sw = (l15 & 7) << 4;
    const char* wbase = (const char*)&Wl[0][0];
    const char* abase = (const char*)Al;

    auto COMPUTE = [&](int bi, int t2){
      bf16x8 a[4][2];
      #pragma unroll
      for (int m = 0; m < 4; ++m)
        #pragma unroll
        for (int h = 0; h < 2; ++h){
          int cb = t2*128 + h*64 + lg*16;
          a[m][h] = *(const bf16x8*)(abase + (m*16 + l15)*512 + (cb ^ sw));
        }
      const char* rb = wbase + bi*16384 + rl*256;
      float4 w00 = *(const float4*)(rb + ((lg*32      ) ^ sw));
      float4 w01 = *(const float4*)(rb + ((lg*32 + 16 ) ^ sw));
      float4 w10 = *(const float4*)(rb + ((lg*32 + 128) ^ sw));
      float4 w11 = *(const float4*)(rb + ((lg*32 + 144) ^ sw));
      bf16x8 wf0 = cvt8(w00, w01);
      bf16x8 wf1 = cvt8(w10, w11);
      #pragma unroll
      for (int m = 0; m < 4; ++m)
        acc[m] = __builtin_amdgcn_mfma_f32_16x16x32_bf16(a[m][0], wf0, acc[m], 0,0,0);
      #pragma unroll
      for (int m = 0; m < 4; ++m)
        acc[m] = __builtin_amdgcn_mfma_f32_16x16x32_bf16(a[m][1], wf1, acc[m], 0,0,0);
    };

    asm volatile("s_waitcnt vmcnt(4)" ::: "memory");
    COMPUTE(0, 0);
    STAGEW(2, 128);
    asm volatile("s_waitcnt vmcnt(4)" ::: "memory");
    COMPUTE(1, 1);
    STAGEW(0, 192);
    asm volatile("s_waitcnt vmcnt(4)" ::: "memory");
    COMPUTE(2, 2);
    asm volatile("s_waitcnt vmcnt(0)" ::: "memory");
    COMPUTE(0, 3);

    float* p = P + (long)blockIdx.y * 64 * N;
    #pragma unroll
    for (int mt = 0; mt < 4; ++mt)
      #pragma unroll
      for (int r = 0; r < 4; ++r){
        int m = mt*16 + lg*4 + r;
        p[(long)m * N + nb + wv*16 + l15] = acc[mt][r];
      }
    __builtin_amdgcn_s_barrier();
  }
}

// ---------------------------------------------------------------------------
// fc: C[64,N] = A[64,2560] @ W[N,2560]^T + bias.
// ---------------------------------------------------------------------------
__global__ __launch_bounds__(256) void gemm_fc2(
    const short* __restrict__ A, int lda,
    const float* __restrict__ W, int sW,
    const float* __restrict__ bias,
    float* __restrict__ C, int N, int reps)
{
  __shared__ short Al[2][64*128];   // 2 x 16 KB
  __shared__ float Wl[3][64*64];    // 3 x 16 KB
  const int wv   = threadIdx.x >> 6;
  const int lane = threadIdx.x & 63;
  const int l15  = lane & 15;
  const int lg   = lane >> 4;
  const int nb   = blockIdx.x * 64;

  for (int r0 = 0; r0 < reps; ++r0){
    const short* Ap = (const short*)launder_u64((unsigned long)A);
    const float* Wp = (const float*)launder_u64((unsigned long)W);

    auto STAGEA = [&](int c){
      short* dst = Al[c & 1];
      #pragma unroll
      for (int i = 0; i < 4; ++i){
        int rbase = wv*16 + i*4;
        int row   = rbase + lg;
        const char* src = (const char*)(Ap + (long)row*lda + c*128)
                          + ((l15*16) ^ ((row & 7) << 4));
        stage16(src, (void*)(dst + rbase*128));
      }
    };
    auto STAGEW = [&](int s){
      float* dst = Wl[s % 3];
      #pragma unroll
      for (int i = 0; i < 4; ++i){
        int row = wv*16 + i*4 + lg;
        const char* src = (const char*)(Wp + (long)(nb + row)*sW + s*64)
                          + ((l15*16) ^ ((row & 7) << 4));
        stage16(src, (void*)(dst + (wv*16 + i*4)*64));
      }
    };

    f32x4 acc[4];
    #pragma unroll
    for (int m = 0; m < 4; ++m) acc[m] = (f32x4){0.f,0.f,0.f,0.f};

    const int rl = wv*16 + l15;
    const int sw = (l15 & 7) << 4;

    auto COMPUTE = [&](int s){
      const char* abase = (const char*)Al[(s >> 1) & 1];
      const int   kh    = (s & 1) * 128;
      bf16x8 a[4][2];
      #pragma unroll
      for (int m = 0; m < 4; ++m)
        #pragma unroll
        for (int h = 0; h < 2; ++h){
          int cb = kh + h*64 + lg*16;
          a[m][h] = *(const bf16x8*)(abase + (m*16 + l15)*256 + (cb ^ sw));
        }
      const char* rb = (const char*)Wl[s % 3] + rl*256;
      float4 w00 = *(const float4*)(rb + ((lg*32      ) ^ sw));
      float4 w01 = *(const float4*)(rb + ((lg*32 + 16 ) ^ sw));
      float4 w10 = *(const float4*)(rb + ((lg*32 + 128) ^ sw));
      float4 w11 = *(const float4*)(rb + ((lg*32 + 144) ^ sw));
      bf16x8 wf0 = cvt8(w00, w01);
      bf16x8 wf1 = cvt8(w10, w11);
      #pragma unroll
      for (int m = 0; m < 4; ++m)
        acc[m] = __builtin_amdgcn_mfma_f32_16x16x32_bf16(a[m][0], wf0, acc[m], 0,0,0);
      #pragma unroll
      for (int m = 0; m < 4; ++m)
        acc[m] = __builtin_amdgcn_mfma_f32_16x16x32_bf16(a[m][1], wf1, acc[m], 0,0,0);
    };

    STAGEA(0); STAGEW(0); STAGEW(1);
    asm volatile("s_waitcnt vmcnt(4)" ::: "memory");
    __builtin_amdgcn_s_barrier();

    STAGEA(1);
    COMPUTE(0);
    STAGEW(2);
    asm volatile("s_waitcnt vmcnt(4)" ::: "memory");
    COMPUTE(1);
    STAGEW(3);
    __builtin_amdgcn_s_barrier();

    for (int c = 1; c < 19; ++c){
      STAGEA(c+1);
      asm volatile("s_waitcnt vmcnt(8)" ::: "memory");
      COMPUTE(2*c);
      STAGEW(2*c+2);
      asm volatile("s_waitcnt vmcnt(4)" ::: "memory");
      COMPUTE(2*c+1);
      STAGEW(2*c+3);
      __builtin_amdgcn_s_barrier();
    }

    asm volatile("s_waitcnt vmcnt(4)" ::: "memory");
    COMPUTE(38);
    asm volatile("s_waitcnt vmcnt(0)" ::: "memory");
    COMPUTE(39);

    const int col = nb + wv*16 + l15;
    const float bn = bias[col];
    #pragma unroll
    for (int mt = 0; mt < 4; ++mt)
      #pragma unroll
      for (int r = 0; r < 4; ++r){
        int m = mt*16 + lg*4 + r;
        C[(long)m * N + col] = acc[mt][r] + bn;
      }
    __builtin_amdgcn_s_barrier();
  }
}

// ---------------------------------------------------------------------------
// energy: atomicAdd only on the LAST rep; earlier reps kept live via asm sink.
// ---------------------------------------------------------------------------
__global__ __launch_bounds__(256) void energy_k(
    const short* __restrict__ encbf, const short* __restrict__ Wbf,
    const float* __restrict__ Ph, const float* __restrict__ attn_b,
    const float* __restrict__ v_w, float* __restrict__ scores, int reps)
{
  const int bx = blockIdx.x;
  const int m3 = bx & 127, n3 = bx >> 7;
  const int wave = threadIdx.x >> 6;
  const int lane = threadIdx.x & 63;
  const int l15  = lane & 15;
  const int lg   = lane >> 4;
  const int mb   = m3 * 64;
  const int nb   = n3 * 64 + wave * 16;
  const int b    = mb >> 7;

  const int hi = b*512 + nb + l15;
  const float hp = attn_b[nb + l15] + Ph[hi] + Ph[32768 + hi]
                 + Ph[65536 + hi] + Ph[98304 + hi];
  const float vn = v_w[nb + l15];

  for (int r0 = 0; r0 < reps; ++r0){
    const short* ap  = (const short*)launder_u64((unsigned long)
                        (encbf + (long)(mb + l15) * 1024)) + lg * 8;
    const short* wpb = (const short*)launder_u64((unsigned long)
                        (Wbf + (long)(nb + l15) * 1024)) + lg * 8;

    f32x4 acc[4] = {};
    bf16x8 wn  = *(const bf16x8*)(wpb);
    bf16x8 an0 = *(const bf16x8*)(ap);
    bf16x8 an1 = *(const bf16x8*)(ap + 16*1024);
    bf16x8 an2 = *(const bf16x8*)(ap + 32*1024);
    bf16x8 an3 = *(const bf16x8*)(ap + 48*1024);
    for (int kb = 32; kb < 1024; kb += 32){
      bf16x8 wc = wn, c0 = an0, c1 = an1, c2 = an2, c3 = an3;
      wn  = *(const bf16x8*)(wpb + kb);
      an0 = *(const bf16x8*)(ap + kb);
      an1 = *(const bf16x8*)(ap + kb + 16*1024);
      an2 = *(const bf16x8*)(ap + kb + 32*1024);
      an3 = *(const bf16x8*)(ap + kb + 48*1024);
      acc[0] = __builtin_amdgcn_mfma_f32_16x16x32_bf16(c0, wc, acc[0], 0,0,0);
      acc[1] = __builtin_amdgcn_mfma_f32_16x16x32_bf16(c1, wc, acc[1], 0,0,0);
      acc[2] = __builtin_amdgcn_mfma_f32_16x16x32_bf16(c2, wc, acc[2], 0,0,0);
      acc[3] = __builtin_amdgcn_mfma_f32_16x16x32_bf16(c3, wc, acc[3], 0,0,0);
    }
    acc[0] = __builtin_amdgcn_mfma_f32_16x16x32_bf16(an0, wn, acc[0], 0,0,0);
    acc[1] = __builtin_amdgcn_mfma_f32_16x16x32_bf16(an1, wn, acc[1], 0,0,0);
    acc[2] = __builtin_amdgcn_mfma_f32_16x16x32_bf16(an2, wn, acc[2], 0,0,0);
    acc[3] = __builtin_amdgcn_mfma_f32_16x16x32_bf16(an3, wn, acc[3], 0,0,0);

    #pragma unroll
    for (int mt = 0; mt < 4; ++mt){
      #pragma unroll
      for (int r = 0; r < 4; ++r){
        int m = mb + mt*16 + lg*4 + r;
        float e = fast_tanh(acc[mt][r] + hp) * vn;
        e += __shfl_xor(e, 1, 16);
        e += __shfl_xor(e, 2, 16);
        e += __shfl_xor(e, 4, 16);
        e += __shfl_xor(e, 8, 16);
        asm volatile("" :: "v"(e));                 // keep all reps live
        if (r0 == reps-1 && l15 == 0) atomicAdd(&scores[m], e);
      }
    }
  }
}

// Fused masked softmax + context
__global__ __launch_bounds__(256) void ctxsm_k(
    const float* __restrict__ sco, const int* __restrict__ mask,
    const short* __restrict__ encbf, float* __restrict__ aw,
    short* __restrict__ A0, short* __restrict__ Zb)
{
  const int bb = blockIdx.x;
  const int t  = threadIdx.x;
  __shared__ float red[128];
  __shared__ float w[128];
  float v = 0.f;
  if (t < 128){
    v = sco[bb*128 + t];
    if (mask[bb*128 + t] == 0) v = -1e10f;
    red[t] = v;
  }
  __syncthreads();
  for (int d = 64; d > 0; d >>= 1){
    if (t < d) red[t] = fmaxf(red[t], red[t + d]);
    __syncthreads();
  }
  const float mx = red[0];
  __syncthreads();
  if (t < 128){
    float e = __expf(v - mx);
    w[t] = e; red[t] = e;
  }
  __syncthreads();
  for (int d = 64; d > 0; d >>= 1){
    if (t < d) red[t] += red[t + d];
    __syncthreads();
  }
  const float inv = 1.f / red[0];
  if (blockIdx.y == 0 && t < 128) aw[bb*128 + t] = w[t] * inv;

  const int dd = blockIdx.y * 256 + t;
  const unsigned short* e = (const unsigned short*)encbf + (long)bb*131072 + dd;
  float s = 0.f;
  #pragma unroll 4
  for (int si = 0; si < 128; ++si){
    float ev = __builtin_bit_cast(float, (unsigned)e[si*1024] << 16);
    s += w[si] * ev;
  }
  s *= inv;
  short vbf = f2bf(s);
  A0[bb*2560 + 512  + dd] = vbf;
  Zb[bb*2560 + 1024 + dd] = vbf;
}

// LSTM epilogue with fused split-K reduce
__global__ __launch_bounds__(256) void lstm_k(
    const float* __restrict__ P, int KS,
    const float* __restrict__ bi, const float* __restrict__ bh,
    const float* __restrict__ c_prev,
    float* __restrict__ h_out, float* __restrict__ c_out,
    short* __restrict__ h_bf, int bf_stride)
{
  const int i = blockIdx.x * 256 + threadIdx.x;
  const int b = i >> 10, n = i & 1023;
  float g4[4];
  #pragma unroll
  for (int gi = 0; gi < 4; ++gi){
    int col = gi*1024 + n;
    float s = bi[col] + bh[col];
    const float* p = P + (long)b*4096 + col;
    for (int sl = 0; sl < KS; ++sl) s += p[(long)sl * 262144];
    g4[gi] = s;
  }
  float iv = fast_sig (g4[0]);
  float fv = fast_sig (g4[1]);
  float gv = fast_tanh(g4[2]);
  float ov = fast_sig (g4[3]);
  float c = fv * c_prev[i] + iv * gv;
  float h = ov * fast_tanh(c);
  c_out[i] = c;
  h_out[i] = h;
  h_bf[(long)b * bf_stride + n] = f2bf(h);
}

extern "C" void kernel_launch(void* const* d_in, const int* in_sizes, int n_in,
                              void* d_out, int out_size, void* d_ws, size_t ws_size,
                              hipStream_t stream)
{
  const int*   tok    = (const int*)  d_in[0];
  const float* hidden = (const float*)d_in[1];
  const float* cell   = (const float*)d_in[2];
  const float* enc    = (const float*)d_in[3];
  const int*   mask   = (const int*)  d_in[4];
  const float* emb    = (const float*)d_in[5];
  const float* attn_w = (const float*)d_in[6];
  const float* attn_b = (const float*)d_in[7];
  const float* v_w    = (const float*)d_in[8];
  const float* w_ih0  = (const float*)d_in[9];
  const float* w_hh0  = (const float*)d_in[10];
  const float* b_ih0  = (const float*)d_in[11];
  const float* b_hh0  = (const float*)d_in[12];
  const float* w_ih1  = (const float*)d_in[13];
  const float* w_hh1  = (const float*)d_in[14];
  const float* b_ih1  = (const float*)d_in[15];
  const float* b_hh1  = (const float*)d_in[16];
  const float* fc_w   = (const float*)d_in[17];
  const float* fc_b   = (const float*)d_in[18];

  float* out  = (float*)d_out;
  float* pred = out;                 // [64,32000]
  float* nh   = out + 2048000;       // [2,64,1024]
  float* nc   = out + 2179072;       // [2,64,1024]
  float* aw   = out + 2310144;       // [64,128]

  char*  wsb   = (char*)d_ws;
  short* encbf = (short*)(wsb + 0);          // 16,777,216 B
  short* Wbf   = (short*)(wsb + 16777216);   //  1,048,576 B
  short* A0    = (short*)(wsb + 17825792);   //    327,680 B
  short* A1    = (short*)(wsb + 18153472);   //    262,144 B
  short* Zb    = (short*)(wsb + 18415616);   //    327,680 B
  float* sco   = (float*)(wsb + 18743296);   //     32,768 B
  float* Pb    = (float*)(wsb + 18776064);   // partials (hproj 4 / gates 10)

  // DIAGNOSTIC multipliers — each giant must exceed ~200us to enter top-5.
  prep_all<<<4404, 256, 0, stream>>>(tok, emb, hidden, enc, attn_w,
                                     encbf, Wbf, A0, A1, Zb, sco, 24);

  gemm_lds<<<dim3(8, 4), 256, 0, stream>>>(A1 + 1024, 2048,
                                           attn_w, 2048, 1<<30, nullptr, 0,
                                           Pb, 512, 1);

  energy_k<<<1024, 256, 0, stream>>>(encbf, Wbf, Pb, attn_b, v_w, sco, 16);

  ctxsm_k<<<dim3(64, 4), 256, 0, stream>>>(sco, mask, encbf, aw, A0, Zb);

  gemm_lds<<<dim3(64, 10), 256, 0, stream>>>(A0, 2560,
                                             w_ih0, 1536, 1536, w_hh0, 1024,
                                             Pb, 4096, 16);
  lstm_k<<<256, 256, 0, stream>>>(Pb, 10, b_ih0, b_hh0, cell,
                                  nh, nc, A1, 2048);

  gemm_lds<<<dim3(64, 8), 256, 0, stream>>>(A1, 2048,
                                            w_ih1, 1024, 1024, w_hh1, 1024,
                                            Pb, 4096, 1);
  lstm_k<<<256, 256, 0, stream>>>(Pb, 8, b_ih1, b_hh1, cell + 65536,
                                  nh + 65536, nc + 65536, Zb, 2560);

  gemm_fc2<<<500, 256, 0, stream>>>(Zb, 2560, fc_w, 2560, fc_b, pred, 32000, 8);
}

// Round 13
// 147.360 us; speedup vs baseline: 12.7307x; 12.7307x over previous
//
#include <hip/hip_runtime.h>

// Decoder step: embed -> additive attention -> 2-layer LSTM -> fc
// B=64, S=128, E=512, H=512, H2=1024, V=32000
// Round 13: energy rebuilt on the LDS-staged counted-vmcnt pipeline (both
// operands streamed via global_load_lds, 3-buffer rotation, barrier/chunk).
// ctxsm ILP-unrolled; lstm KS templated. Rest = round-9 (218us) kernels.

typedef __attribute__((ext_vector_type(8))) short bf16x8;
typedef __attribute__((ext_vector_type(4))) float f32x4;

__device__ __forceinline__ short f2bf(float f){
  __bf16 h = (__bf16)f;
  return __builtin_bit_cast(short, h);
}

__device__ __forceinline__ bf16x8 cvt8(float4 a, float4 b){
  bf16x8 r;
  r[0]=f2bf(a.x); r[1]=f2bf(a.y); r[2]=f2bf(a.z); r[3]=f2bf(a.w);
  r[4]=f2bf(b.x); r[5]=f2bf(b.y); r[6]=f2bf(b.z); r[7]=f2bf(b.w);
  return r;
}

__device__ __forceinline__ bf16x8 ld8_bf(const float* __restrict__ p){
  return cvt8(*(const float4*)p, *(const float4*)(p + 4));
}

__device__ __forceinline__ float fast_tanh(float x){
  x = fminf(fmaxf(x, -15.f), 15.f);
  float t = __expf(2.f * x);
  return (t - 1.f) / (t + 1.f);
}
__device__ __forceinline__ float fast_sig(float x){
  return 1.f / (1.f + __expf(-x));
}

__device__ __forceinline__ void stage16(const void* src, void* dst_lds){
  __builtin_amdgcn_global_load_lds(
      (const __attribute__((address_space(1))) void*)src,
      (__attribute__((address_space(3))) void*)dst_lds, 16, 0, 0);
}

// ---------------------------------------------------------------------------
// Fused prep: enc->bf16, attn_w[:,1024:2048]->bf16, emb gather, hidden cvt,
// scores zero.
// ---------------------------------------------------------------------------
__global__ __launch_bounds__(256) void prep_all(
    const int* __restrict__ tok, const float* __restrict__ emb,
    const float* __restrict__ hidden, const float* __restrict__ enc,
    const float* __restrict__ attn_w,
    short* __restrict__ encbf, short* __restrict__ Wbf,
    short* __restrict__ A0, short* __restrict__ A1, short* __restrict__ Zb,
    float* __restrict__ sco)
{
  const int bid = blockIdx.x, t = threadIdx.x;
  if (bid < 4096){
    long i = ((long)bid*256 + t)*8;
    *(bf16x8*)(encbf + i) = ld8_bf(enc + i);
  } else if (bid < 4352){
    int j = (bid-4096)*256 + t;
    int r = j >> 7, c = (j & 127)*8;
    *(bf16x8*)(Wbf + r*1024 + c) = ld8_bf(attn_w + (long)r*2048 + 1024 + c);
  } else if (bid < 4368){
    int j = (bid-4352)*256 + t;
    int b = j >> 6, e8 = (j & 63)*8;
    bf16x8 v = ld8_bf(emb + (long)tok[b]*512 + e8);
    *(bf16x8*)(A0 + b*2560 + e8) = v;
    *(bf16x8*)(Zb + b*2560 + 2048 + e8) = v;
  } else if (bid < 4400){
    int j = (bid-4368)*256 + t;
    int b = j >> 7, n8 = (j & 127)*8;
    *(bf16x8*)(A0 + b*2560 + 1536 + n8) = ld8_bf(hidden + (long)b*1024 + n8);
    *(bf16x8*)(A1 + b*2048 + 1024 + n8) = ld8_bf(hidden + 65536 + (long)b*1024 + n8);
  } else {
    int j = (bid-4400)*256 + t;
    float4 z = {0.f, 0.f, 0.f, 0.f};
    *(float4*)(sco + j*8) = z;
    *(float4*)(sco + j*8 + 4) = z;
  }
}

// ---------------------------------------------------------------------------
// P[by][64][N] = A_bf16[64,K] @ [W1|W2][N,:]^T on a 256-wide k-slice.
// (hproj + LSTM gates; split-K partials, consumer reduces)
// ---------------------------------------------------------------------------
#define KSL 256
__global__ __launch_bounds__(256) void gemm_lds(
    const short* __restrict__ A, int lda,
    const float* __restrict__ W1, int sW1, int K1,
    const float* __restrict__ W2, int sW2,
    float* __restrict__ P, int N)
{
  __shared__ short Al[64*256];     // 32 KB
  __shared__ float Wl[3][64*64];   // 48 KB
  const int wv   = threadIdx.x >> 6;
  const int lane = threadIdx.x & 63;
  const int l15  = lane & 15;
  const int lg   = lane >> 4;
  const int nb   = blockIdx.x * 64;
  const int k0   = blockIdx.y * KSL;

  const float* W; int sW, koff;
  if (k0 < K1){ W = W1; sW = sW1; koff = k0; }
  else        { W = W2; sW = sW2; koff = k0 - K1; }

  {
    const int r2  = lane >> 5;
    const int c16 = (lane & 31) * 16;
    #pragma unroll
    for (int i = 0; i < 8; ++i){
      int rbase = wv*16 + i*2;
      int row   = rbase + r2;
      const char* src = (const char*)A + (long)row*lda*2 + (long)k0*2
                        + (c16 ^ ((row & 7) << 4));
      stage16(src, (void*)(Al + rbase*256));
    }
  }

  auto STAGEW = [&](int bi, int kbase){
    #pragma unroll
    for (int i = 0; i < 4; ++i){
      int row = wv*16 + i*4 + lg;
      const char* src = (const char*)(W + (long)(nb + row)*sW + koff + kbase)
                        + ((l15*16) ^ ((row & 7) << 4));
      stage16(src, (void*)&Wl[bi][(wv*16 + i*4)*64]);
    }
  };

  STAGEW(0, 0);
  STAGEW(1, 64);
  asm volatile("s_waitcnt vmcnt(8)" ::: "memory");
  asm volatile("s_barrier" ::: "memory");

  f32x4 acc[4];
  #pragma unroll
  for (int m = 0; m < 4; ++m) acc[m] = (f32x4){0.f,0.f,0.f,0.f};

  const int  rl = wv*16 + l15;
  const int  sw = (l15 & 7) << 4;
  const char* wbase = (const char*)&Wl[0][0];
  const char* abase = (const char*)Al;

  auto COMPUTE = [&](int bi, int t){
    bf16x8 a[4][2];
    #pragma unroll
    for (int m = 0; m < 4; ++m)
      #pragma unroll
      for (int h = 0; h < 2; ++h){
        int cb = t*128 + h*64 + lg*16;
        a[m][h] = *(const bf16x8*)(abase + (m*16 + l15)*512 + (cb ^ sw));
      }
    const char* rb = wbase + bi*16384 + rl*256;
    float4 w00 = *(const float4*)(rb + ((lg*32      ) ^ sw));
    float4 w01 = *(const float4*)(rb + ((lg*32 + 16 ) ^ sw));
    float4 w10 = *(const float4*)(rb + ((lg*32 + 128) ^ sw));
    float4 w11 = *(const float4*)(rb + ((lg*32 + 144) ^ sw));
    bf16x8 wf0 = cvt8(w00, w01);
    bf16x8 wf1 = cvt8(w10, w11);
    #pragma unroll
    for (int m = 0; m < 4; ++m)
      acc[m] = __builtin_amdgcn_mfma_f32_16x16x32_bf16(a[m][0], wf0, acc[m], 0,0,0);
    #pragma unroll
    for (int m = 0; m < 4; ++m)
      acc[m] = __builtin_amdgcn_mfma_f32_16x16x32_bf16(a[m][1], wf1, acc[m], 0,0,0);
  };

  asm volatile("s_waitcnt vmcnt(4)" ::: "memory");
  COMPUTE(0, 0);
  STAGEW(2, 128);
  asm volatile("s_waitcnt vmcnt(4)" ::: "memory");
  COMPUTE(1, 1);
  STAGEW(0, 192);
  asm volatile("s_waitcnt vmcnt(4)" ::: "memory");
  COMPUTE(2, 2);
  asm volatile("s_waitcnt vmcnt(0)" ::: "memory");
  COMPUTE(0, 3);

  float* p = P + (long)blockIdx.y * 64 * N;
  #pragma unroll
  for (int mt = 0; mt < 4; ++mt)
    #pragma unroll
    for (int r = 0; r < 4; ++r){
      int m = mt*16 + lg*4 + r;
      p[(long)m * N + nb + wv*16 + l15] = acc[mt][r];
    }
}

// ---------------------------------------------------------------------------
// fc: C[64,N] = A[64,2560] @ W[N,2560]^T + bias. Full K, 2 blocks/CU,
// per-wave-private W streams, A double-buffered per 128-k chunk.
// ---------------------------------------------------------------------------
__global__ __launch_bounds__(256) void gemm_fc2(
    const short* __restrict__ A, int lda,
    const float* __restrict__ W, int sW,
    const float* __restrict__ bias,
    float* __restrict__ C, int N)
{
  __shared__ short Al[2][64*128];   // 2 x 16 KB
  __shared__ float Wl[3][64*64];    // 3 x 16 KB
  const int wv   = threadIdx.x >> 6;
  const int lane = threadIdx.x & 63;
  const int l15  = lane & 15;
  const int lg   = lane >> 4;
  const int nb   = blockIdx.x * 64;

  auto STAGEA = [&](int c){
    short* dst = Al[c & 1];
    #pragma unroll
    for (int i = 0; i < 4; ++i){
      int rbase = wv*16 + i*4;
      int row   = rbase + lg;
      const char* src = (const char*)(A + (long)row*lda + c*128)
                        + ((l15*16) ^ ((row & 7) << 4));
      stage16(src, (void*)(dst + rbase*128));
    }
  };
  auto STAGEW = [&](int s){
    float* dst = Wl[s % 3];
    #pragma unroll
    for (int i = 0; i < 4; ++i){
      int row = wv*16 + i*4 + lg;
      const char* src = (const char*)(W + (long)(nb + row)*sW + s*64)
                        + ((l15*16) ^ ((row & 7) << 4));
      stage16(src, (void*)(dst + (wv*16 + i*4)*64));
    }
  };

  f32x4 acc[4];
  #pragma unroll
  for (int m = 0; m < 4; ++m) acc[m] = (f32x4){0.f,0.f,0.f,0.f};

  const int rl = wv*16 + l15;
  const int sw = (l15 & 7) << 4;

  auto COMPUTE = [&](int s){
    const char* abase = (const char*)Al[(s >> 1) & 1];
    const int   kh    = (s & 1) * 128;
    bf16x8 a[4][2];
    #pragma unroll
    for (int m = 0; m < 4; ++m)
      #pragma unroll
      for (int h = 0; h < 2; ++h){
        int cb = kh + h*64 + lg*16;
        a[m][h] = *(const bf16x8*)(abase + (m*16 + l15)*256 + (cb ^ sw));
      }
    const char* rb = (const char*)Wl[s % 3] + rl*256;
    float4 w00 = *(const float4*)(rb + ((lg*32      ) ^ sw));
    float4 w01 = *(const float4*)(rb + ((lg*32 + 16 ) ^ sw));
    float4 w10 = *(const float4*)(rb + ((lg*32 + 128) ^ sw));
    float4 w11 = *(const float4*)(rb + ((lg*32 + 144) ^ sw));
    bf16x8 wf0 = cvt8(w00, w01);
    bf16x8 wf1 = cvt8(w10, w11);
    #pragma unroll
    for (int m = 0; m < 4; ++m)
      acc[m] = __builtin_amdgcn_mfma_f32_16x16x32_bf16(a[m][0], wf0, acc[m], 0,0,0);
    #pragma unroll
    for (int m = 0; m < 4; ++m)
      acc[m] = __builtin_amdgcn_mfma_f32_16x16x32_bf16(a[m][1], wf1, acc[m], 0,0,0);
  };

  STAGEA(0); STAGEW(0); STAGEW(1);
  asm volatile("s_waitcnt vmcnt(4)" ::: "memory");
  __builtin_amdgcn_s_barrier();

  STAGEA(1);
  COMPUTE(0);
  STAGEW(2);
  asm volatile("s_waitcnt vmcnt(4)" ::: "memory");
  COMPUTE(1);
  STAGEW(3);
  __builtin_amdgcn_s_barrier();

  for (int c = 1; c < 19; ++c){
    STAGEA(c+1);
    asm volatile("s_waitcnt vmcnt(8)" ::: "memory");
    COMPUTE(2*c);
    STAGEW(2*c+2);
    asm volatile("s_waitcnt vmcnt(4)" ::: "memory");
    COMPUTE(2*c+1);
    STAGEW(2*c+3);
    __builtin_amdgcn_s_barrier();
  }

  asm volatile("s_waitcnt vmcnt(4)" ::: "memory");
  COMPUTE(38);
  asm volatile("s_waitcnt vmcnt(0)" ::: "memory");
  COMPUTE(39);

  const int col = nb + wv*16 + l15;
  const float bn = bias[col];
  #pragma unroll
  for (int mt = 0; mt < 4; ++mt)
    #pragma unroll
    for (int r = 0; r < 4; ++r){
      int m = mt*16 + lg*4 + r;
      C[(long)m * N + col] = acc[mt][r] + bn;
    }
}

// ---------------------------------------------------------------------------
// energy: T = encbf[8192,1024] @ Wbf[512,1024]^T ; scores += v.tanh(T+hproj).
// Both operands streamed to LDS via global_load_lds in 64-k chunks, 3-buffer
// rotation, counted vmcnt(4) (never 0 mid-loop), one 4-wave barrier/chunk
// (enc rows are cross-wave shared). XOR-swizzle via pre-swizzled source.
// grid 1024: m3 = bx&127 -> all 8 n-blocks of an m-tile share an XCD L2.
// ---------------------------------------------------------------------------
__global__ __launch_bounds__(256) void energy_lds(
    const short* __restrict__ encbf, const short* __restrict__ Wbf,
    const float* __restrict__ Ph, const float* __restrict__ attn_b,
    const float* __restrict__ v_w, float* __restrict__ scores)
{
  __shared__ short Ab[3][64*64];   // enc chunks, 24 KB
  __shared__ short Bb[3][64*64];   // Wbf chunks, 24 KB
  const int bx   = blockIdx.x;
  const int m3   = bx & 127, n3 = bx >> 7;
  const int wv   = threadIdx.x >> 6;
  const int lane = threadIdx.x & 63;
  const int l15  = lane & 15;
  const int lg   = lane >> 4;
  const int mb   = m3 * 64;
  const int nbg  = n3 * 64;
  const int nb   = nbg + wv * 16;
  const int b    = mb >> 7;

  const int hi = b*512 + nb + l15;
  const float hp = attn_b[nb + l15] + Ph[hi] + Ph[32768 + hi]
                 + Ph[65536 + hi] + Ph[98304 + hi];
  const float vn = v_w[nb + l15];

  const int srow = lane >> 3;          // row within 8-row group
  const int scb  = (lane & 7) * 16;    // byte col within 128B row

  auto STAGE = [&](int c, int kb){
    short* da = Ab[c % 3];
    short* db = Bb[c % 3];
    #pragma unroll
    for (int i = 0; i < 2; ++i){
      int rbase = wv*16 + i*8;
      int row   = rbase + srow;
      int swz   = scb ^ ((row & 7) << 4);
      const char* sa = (const char*)(encbf + (long)(mb + row)*1024 + kb) + swz;
      stage16(sa, (void*)(da + rbase*64));
      const char* sb = (const char*)(Wbf + (long)(nbg + row)*1024 + kb) + swz;
      stage16(sb, (void*)(db + rbase*64));
    }
  };

  f32x4 acc[4] = {};
  const int brow = wv*16 + l15;
  const int bswz = (brow & 7) << 4;
  const int aswz = (l15 & 7) << 4;     // arow&7 == l15&7 for all m-tiles

  auto COMPUTE = [&](int c){
    const char* ab = (const char*)Ab[c % 3];
    const char* bb = (const char*)Bb[c % 3];
    #pragma unroll
    for (int h = 0; h < 2; ++h){
      const int colb = h*64 + lg*16;
      bf16x8 bf_ = *(const bf16x8*)(bb + brow*128 + (colb ^ bswz));
      #pragma unroll
      for (int m = 0; m < 4; ++m){
        const int arow = m*16 + l15;
        bf16x8 af = *(const bf16x8*)(ab + arow*128 + (colb ^ aswz));
        acc[m] = __builtin_amdgcn_mfma_f32_16x16x32_bf16(af, bf_, acc[m], 0,0,0);
      }
    }
  };

  STAGE(0, 0);
  STAGE(1, 64);
  for (int c = 0; c < 14; ++c){
    asm volatile("s_waitcnt vmcnt(4)" ::: "memory");   // chunk c landed (wave)
    __builtin_amdgcn_s_barrier();                      // all waves' chunk c
    COMPUTE(c);
    STAGE(c+2, (c+2)*64);
  }
  asm volatile("s_waitcnt vmcnt(4)" ::: "memory");
  __builtin_amdgcn_s_barrier();
  COMPUTE(14);
  asm volatile("s_waitcnt vmcnt(0)" ::: "memory");
  __builtin_amdgcn_s_barrier();
  COMPUTE(15);

  #pragma unroll
  for (int mt = 0; mt < 4; ++mt){
    #pragma unroll
    for (int r = 0; r < 4; ++r){
      int m = mb + mt*16 + lg*4 + r;
      float e = fast_tanh(acc[mt][r] + hp) * vn;
      e += __shfl_xor(e, 1, 16);
      e += __shfl_xor(e, 2, 16);
      e += __shfl_xor(e, 4, 16);
      e += __shfl_xor(e, 8, 16);
      if (l15 == 0) atomicAdd(&scores[m], e);
    }
  }
}

// Fused masked softmax + context (ILP: 4 accumulators, deep unroll)
__global__ __launch_bounds__(256) void ctxsm_k(
    const float* __restrict__ sco, const int* __restrict__ mask,
    const short* __restrict__ encbf, float* __restrict__ aw,
    short* __restrict__ A0, short* __restrict__ Zb)
{
  const int bb = blockIdx.x;
  const int t  = threadIdx.x;
  __shared__ float red[128];
  __shared__ float w[128];
  float v = 0.f;
  if (t < 128){
    v = sco[bb*128 + t];
    if (mask[bb*128 + t] == 0) v = -1e10f;
    red[t] = v;
  }
  __syncthreads();
  for (int d = 64; d > 0; d >>= 1){
    if (t < d) red[t] = fmaxf(red[t], red[t + d]);
    __syncthreads();
  }
  const float mx = red[0];
  __syncthreads();
  if (t < 128){
    float e = __expf(v - mx);
    w[t] = e; red[t] = e;
  }
  __syncthreads();
  for (int d = 64; d > 0; d >>= 1){
    if (t < d) red[t] += red[t + d];
    __syncthreads();
  }
  const float inv = 1.f / red[0];
  if (blockIdx.y == 0 && t < 128) aw[bb*128 + t] = w[t] * inv;

  const int dd = blockIdx.y * 256 + t;
  const unsigned short* e = (const unsigned short*)encbf + (long)bb*131072 + dd;
  float s0 = 0.f, s1 = 0.f, s2 = 0.f, s3 = 0.f;
  #pragma unroll 8
  for (int si = 0; si < 128; si += 4){
    s0 += w[si  ] * __builtin_bit_cast(float, (unsigned)e[(si  )*1024] << 16);
    s1 += w[si+1] * __builtin_bit_cast(float, (unsigned)e[(si+1)*1024] << 16);
    s2 += w[si+2] * __builtin_bit_cast(float, (unsigned)e[(si+2)*1024] << 16);
    s3 += w[si+3] * __builtin_bit_cast(float, (unsigned)e[(si+3)*1024] << 16);
  }
  float s = ((s0 + s1) + (s2 + s3)) * inv;
  short vbf = f2bf(s);
  A0[bb*2560 + 512  + dd] = vbf;
  Zb[bb*2560 + 1024 + dd] = vbf;
}

// LSTM epilogue with fused split-K reduce (KS templated -> full unroll)
template<int KS>
__global__ __launch_bounds__(256) void lstm_k(
    const float* __restrict__ P,
    const float* __restrict__ bi, const float* __restrict__ bh,
    const float* __restrict__ c_prev,
    float* __restrict__ h_out, float* __restrict__ c_out,
    short* __restrict__ h_bf, int bf_stride)
{
  const int i = blockIdx.x * 256 + threadIdx.x;
  const int b = i >> 10, n = i & 1023;
  float g4[4];
  #pragma unroll
  for (int gi = 0; gi < 4; ++gi){
    int col = gi*1024 + n;
    float s = bi[col] + bh[col];
    const float* p = P + (long)b*4096 + col;
    #pragma unroll
    for (int sl = 0; sl < KS; ++sl) s += p[(long)sl * 262144];
    g4[gi] = s;
  }
  float iv = fast_sig (g4[0]);
  float fv = fast_sig (g4[1]);
  float gv = fast_tanh(g4[2]);
  float ov = fast_sig (g4[3]);
  float c = fv * c_prev[i] + iv * gv;
  float h = ov * fast_tanh(c);
  c_out[i] = c;
  h_out[i] = h;
  h_bf[(long)b * bf_stride + n] = f2bf(h);
}

extern "C" void kernel_launch(void* const* d_in, const int* in_sizes, int n_in,
                              void* d_out, int out_size, void* d_ws, size_t ws_size,
                              hipStream_t stream)
{
  const int*   tok    = (const int*)  d_in[0];
  const float* hidden = (const float*)d_in[1];
  const float* cell   = (const float*)d_in[2];
  const float* enc    = (const float*)d_in[3];
  const int*   mask   = (const int*)  d_in[4];
  const float* emb    = (const float*)d_in[5];
  const float* attn_w = (const float*)d_in[6];
  const float* attn_b = (const float*)d_in[7];
  const float* v_w    = (const float*)d_in[8];
  const float* w_ih0  = (const float*)d_in[9];
  const float* w_hh0  = (const float*)d_in[10];
  const float* b_ih0  = (const float*)d_in[11];
  const float* b_hh0  = (const float*)d_in[12];
  const float* w_ih1  = (const float*)d_in[13];
  const float* w_hh1  = (const float*)d_in[14];
  const float* b_ih1  = (const float*)d_in[15];
  const float* b_hh1  = (const float*)d_in[16];
  const float* fc_w   = (const float*)d_in[17];
  const float* fc_b   = (const float*)d_in[18];

  float* out  = (float*)d_out;
  float* pred = out;                 // [64,32000]
  float* nh   = out + 2048000;       // [2,64,1024]
  float* nc   = out + 2179072;       // [2,64,1024]
  float* aw   = out + 2310144;       // [64,128]

  char*  wsb   = (char*)d_ws;
  short* encbf = (short*)(wsb + 0);          // 16,777,216 B
  short* Wbf   = (short*)(wsb + 16777216);   //  1,048,576 B
  short* A0    = (short*)(wsb + 17825792);   //    327,680 B
  short* A1    = (short*)(wsb + 18153472);   //    262,144 B
  short* Zb    = (short*)(wsb + 18415616);   //    327,680 B
  float* sco   = (float*)(wsb + 18743296);   //     32,768 B
  float* Pb    = (float*)(wsb + 18776064);   // partials (hproj 4 / gates 10)

  prep_all<<<4404, 256, 0, stream>>>(tok, emb, hidden, enc, attn_w,
                                     encbf, Wbf, A0, A1, Zb, sco);

  // hproj partials = h_top @ attn_w[:,0:1024]^T  (4 x 256-k slices)
  gemm_lds<<<dim3(8, 4), 256, 0, stream>>>(A1 + 1024, 2048,
                                           attn_w, 2048, 1<<30, nullptr, 0,
                                           Pb, 512);

  energy_lds<<<1024, 256, 0, stream>>>(encbf, Wbf, Pb, attn_b, v_w, sco);

  ctxsm_k<<<dim3(64, 4), 256, 0, stream>>>(sco, mask, encbf, aw, A0, Zb);

  // layer 0: A0 = [emb | ctx | h0_prev], W = [w_ih0 | w_hh0], K=2560
  gemm_lds<<<dim3(64, 10), 256, 0, stream>>>(A0, 2560,
                                             w_ih0, 1536, 1536, w_hh0, 1024,
                                             Pb, 4096);
  lstm_k<10><<<256, 256, 0, stream>>>(Pb, b_ih0, b_hh0, cell,
                                      nh, nc, A1, 2048);

  // layer 1: A1 = [h0' | h1_prev], W = [w_ih1 | w_hh1], K=2048
  gemm_lds<<<dim3(64, 8), 256, 0, stream>>>(A1, 2048,
                                            w_ih1, 1024, 1024, w_hh1, 1024,
                                            Pb, 4096);
  lstm_k<8><<<256, 256, 0, stream>>>(Pb, b_ih1, b_hh1, cell + 65536,
                                     nh + 65536, nc + 65536, Zb, 2560);

  // prediction = Zb @ fc_w^T + fc_b
  gemm_fc2<<<500, 256, 0, stream>>>(Zb, 2560, fc_w, 2560, fc_b, pred, 32000);
}